// Round 1
// baseline (861.581 us; speedup 1.0000x reference)
//
#include <hip/hip_runtime.h>
#include <cmath>

#define N_ENT 100000
#define EHALF 1000000
#define N_REL 500

#ifndef M_PI
#define M_PI 3.14159265358979323846
#endif

// ---------------- DFT tables ----------------
// Spectrum layout per row (128 floats): slot0=Re(bin0), slot1=Re(bin64),
// slot 2f=Re(bin f), slot 2f+1=Im(bin f) for f=1..63.
// Ftab[n][slot]: x(128) @ Ftab -> spectrum.  (rfft)
// Gtab[slot][n]: spectrum @ (Gtab @ W) -> irfft(spec) @ W, with 1/3 folded in.
__global__ void k_tabs(float* __restrict__ Ftab, float* __restrict__ Gtab) {
  int i = blockIdx.x * 256 + threadIdx.x;
  if (i >= 128 * 128) return;
  int n = i >> 7, s = i & 127;
  float fv, gv;
  if (s == 0) { fv = 1.f; gv = 1.f / 384.f; }
  else if (s == 1) { float sg = (n & 1) ? -1.f : 1.f; fv = sg; gv = sg / 384.f; }
  else {
    int f = s >> 1;
    double ang = 2.0 * M_PI * (double)((f * n) & 127) / 128.0;
    if (!(s & 1)) { double c = cos(ang); fv = (float)c; gv = (float)(c * (2.0 / 384.0)); }
    else { double sv = sin(ang); fv = (float)(-sv); gv = (float)(-sv * (2.0 / 384.0)); }
  }
  Ftab[n * 128 + s] = fv;
  Gtab[s * 128 + n] = gv;
}

// Rf[r] = spectrum of rel_all[r], r in [0,501); row 500 = loop_rel
__global__ void k_dftrel(const float* __restrict__ rel, const float* __restrict__ looprel,
                         const float* __restrict__ Ftab, float* __restrict__ Rf) {
  int r = blockIdx.x, s = threadIdx.x;
  const float* row = (r < N_REL) ? rel + (size_t)r * 128 : looprel;
  float acc = 0.f;
  for (int n = 0; n < 128; ++n) acc += row[n] * Ftab[n * 128 + s];
  Rf[(size_t)r * 128 + s] = acc;
}

// Rotate Gw_loop rows by loop-rel spectrum: folds c_loop = conj(Xf)*Rf_loop
// so that out_loop = Xf @ Wl'.
__global__ void k_rotloop(float* __restrict__ Wl, const float* __restrict__ Rfl) {
  int c = threadIdx.x;  // 128
  int f = blockIdx.x;   // 0..63
  if (f == 0) {
    Wl[c]       = Rfl[0] * Wl[c];
    Wl[128 + c] = Rfl[1] * Wl[128 + c];
  } else {
    float rr = Rfl[2 * f], ri = Rfl[2 * f + 1];
    float a = Wl[2 * f * 128 + c], b = Wl[(2 * f + 1) * 128 + c];
    Wl[2 * f * 128 + c]       = rr * a + ri * b;
    Wl[(2 * f + 1) * 128 + c] = ri * a - rr * b;
  }
}

// ---------------- generic fp32 GEMM, N fixed = 128 ----------------
// C[M x 128] = A[M x K](lda) @ B[K x 128]; optional bias add; optional BN
// partial sums (sum, sumsq per column) atomically accumulated into bnAcc[256].
__global__ __launch_bounds__(256) void gemm128(
    const float* __restrict__ A, int lda,
    const float* __restrict__ B,
    float* __restrict__ C, int ldc,
    int M, int K,
    const float* __restrict__ bias,
    float* __restrict__ bnAcc) {
  __shared__ float As[64][64];
  __shared__ float Bs[64][128];
  const int t = threadIdx.x;
  const int m0 = blockIdx.x * 64;
  const int cg = t & 31;   // cols 4cg..4cg+3
  const int eg = t >> 5;   // rows 8eg..8eg+7
  float acc[8][4];
#pragma unroll
  for (int i = 0; i < 8; ++i)
#pragma unroll
    for (int j = 0; j < 4; ++j) acc[i][j] = 0.f;

  for (int k0 = 0; k0 < K; k0 += 64) {
#pragma unroll
    for (int p = 0; p < 4; ++p) {
      int idx = t + p * 256;
      int r = idx >> 4, c4 = idx & 15;
      int gr = m0 + r;
      float4 v = make_float4(0.f, 0.f, 0.f, 0.f);
      if (gr < M) v = *(const float4*)(A + (size_t)gr * lda + k0 + c4 * 4);
      *(float4*)&As[r][c4 * 4] = v;
    }
#pragma unroll
    for (int p = 0; p < 8; ++p) {
      int idx = t + p * 256;
      int r = idx >> 5, c4 = idx & 31;
      float4 v = *(const float4*)(B + (size_t)(k0 + r) * 128 + c4 * 4);
      *(float4*)&Bs[r][c4 * 4] = v;
    }
    __syncthreads();
#pragma unroll
    for (int k = 0; k < 64; ++k) {
      float4 bv = *(float4*)&Bs[k][cg * 4];
#pragma unroll
      for (int i = 0; i < 8; ++i) {
        float av = As[eg * 8 + i][k];
        acc[i][0] += av * bv.x; acc[i][1] += av * bv.y;
        acc[i][2] += av * bv.z; acc[i][3] += av * bv.w;
      }
    }
    __syncthreads();
  }

  float bx = 0, by = 0, bz = 0, bw = 0;
  if (bias) { bx = bias[cg * 4]; by = bias[cg * 4 + 1]; bz = bias[cg * 4 + 2]; bw = bias[cg * 4 + 3]; }
  float sv[4] = {0, 0, 0, 0}, qv[4] = {0, 0, 0, 0};
#pragma unroll
  for (int i = 0; i < 8; ++i) {
    int gr = m0 + eg * 8 + i;
    if (gr < M) {
      float4 v = make_float4(acc[i][0] + bx, acc[i][1] + by, acc[i][2] + bz, acc[i][3] + bw);
      *(float4*)(C + (size_t)gr * ldc + cg * 4) = v;
      if (bnAcc) {
        sv[0] += v.x; sv[1] += v.y; sv[2] += v.z; sv[3] += v.w;
        qv[0] += v.x * v.x; qv[1] += v.y * v.y; qv[2] += v.z * v.z; qv[3] += v.w * v.w;
      }
    }
  }
  if (bnAcc) {
    __syncthreads();
    float* S = (float*)As;       // 1024 floats
    float* Q = S + 1024;         // 1024 floats (fits in As[64][64])
#pragma unroll
    for (int j = 0; j < 4; ++j) { S[eg * 128 + cg * 4 + j] = sv[j]; Q[eg * 128 + cg * 4 + j] = qv[j]; }
    __syncthreads();
    if (t < 128) {
      float a = 0, b = 0;
#pragma unroll
      for (int g = 0; g < 8; ++g) { a += S[g * 128 + t]; b += Q[g * 128 + t]; }
      atomicAdd(&bnAcc[t], a);
      atomicAdd(&bnAcc[128 + t], b);
    }
  }
}

// ---------------- edge preprocessing ----------------
__global__ void k_hist(const int* __restrict__ ei,
                       int* degIn, int* cntIn, int* degOut, int* cntOut) {
  int e = blockIdx.x * 256 + threadIdx.x;
  if (e >= EHALF) return;
  atomicAdd(&degIn[ei[e]], 1);
  atomicAdd(&cntIn[ei[2 * EHALF + e]], 1);
  atomicAdd(&degOut[ei[EHALF + e]], 1);
  atomicAdd(&cntOut[ei[3 * EHALF + e]], 1);
}

__global__ void k_dinv(const int* __restrict__ deg, float* __restrict__ dinv) {
  int v = blockIdx.x * 256 + threadIdx.x;
  if (v >= N_ENT) return;
  int d = deg[v];
  dinv[v] = (d > 0) ? rsqrtf((float)d) : 0.f;
}

__global__ void k_scan1(const int* __restrict__ cnt, int n, int* __restrict__ partials) {
  __shared__ int sd[256];
  int base = blockIdx.x * 1024, t = threadIdx.x;
  int s = 0;
#pragma unroll
  for (int j = 0; j < 4; ++j) { int i = base + t * 4 + j; if (i < n) s += cnt[i]; }
  sd[t] = s; __syncthreads();
  for (int o = 128; o > 0; o >>= 1) { if (t < o) sd[t] += sd[t + o]; __syncthreads(); }
  if (t == 0) partials[blockIdx.x] = sd[0];
}

__global__ void k_scan2(int* __restrict__ partials, int nb) {
  __shared__ int sd[256];
  int t = threadIdx.x;
  int v = (t < nb) ? partials[t] : 0;
  sd[t] = v; __syncthreads();
  for (int o = 1; o < 256; o <<= 1) {
    int add = (t >= o) ? sd[t - o] : 0;
    __syncthreads();
    sd[t] += add;
    __syncthreads();
  }
  if (t < nb) partials[t] = sd[t] - v;  // exclusive
}

__global__ void k_scan3(const int* __restrict__ cnt, int n,
                        const int* __restrict__ partials, int* __restrict__ off) {
  __shared__ int sd[256];
  int base = blockIdx.x * 1024, t = threadIdx.x;
  int c[4]; int s = 0;
#pragma unroll
  for (int j = 0; j < 4; ++j) { int i = base + t * 4 + j; c[j] = (i < n) ? cnt[i] : 0; s += c[j]; }
  sd[t] = s; __syncthreads();
  for (int o = 1; o < 256; o <<= 1) {
    int add = (t >= o) ? sd[t - o] : 0;
    __syncthreads();
    sd[t] += add;
    __syncthreads();
  }
  int excl = sd[t] - s + partials[blockIdx.x];
#pragma unroll
  for (int j = 0; j < 4; ++j) { int i = base + t * 4 + j; if (i < n) off[i] = excl; excl += c[j]; }
}

__global__ void k_scatter(const int* __restrict__ ei, const int* __restrict__ et,
                          int* curIn, int* curOut,
                          int* __restrict__ sortedIn, int* __restrict__ sortedOut) {
  int e = blockIdx.x * 256 + threadIdx.x;
  if (e >= EHALF) return;
  {
    int src = ei[e], dst = ei[2 * EHALF + e], typ = et[e];
    int pos = atomicAdd(&curIn[dst], 1);
    sortedIn[pos] = src | (typ << 17);
  }
  {
    int src = ei[EHALF + e], dst = ei[3 * EHALF + e], typ = et[EHALF + e];
    int pos = atomicAdd(&curOut[dst], 1);
    sortedOut[pos] = src | (typ << 17);
  }
}

// ---------------- frequency-domain edge aggregation ----------------
// Abuf row v (384 floats): [c_in spectrum 128 | c_out spectrum 128 | Xf 128].
// Wave per entity; lane l owns complex bin l (lane 0: the two real bins 0/64).
__global__ __launch_bounds__(256) void k_agg(
    float* __restrict__ Abuf, const float* __restrict__ Rf,
    const int* __restrict__ sortedIn, const int* __restrict__ offIn, const float* __restrict__ dinvIn,
    const int* __restrict__ sortedOut, const int* __restrict__ offOut, const float* __restrict__ dinvOut) {
  int w = threadIdx.x >> 6, l = threadIdx.x & 63;
  int v = blockIdx.x * 4 + w;
  if (v >= N_ENT) return;
  const float2* X2 = (const float2*)Abuf;  // row stride 192 float2; Xf at +128
  const float2* R2 = (const float2*)Rf;
  float2* A2 = (float2*)Abuf;

  float cix = 0.f, ciy = 0.f;
  {
    float dv = dinvIn[v];
    int b = offIn[v];
    int e = (v + 1 < N_ENT) ? offIn[v + 1] : EHALF;
    for (int i = b; i < e; ++i) {
      int pe = sortedIn[i];
      int src = pe & 131071, typ = pe >> 17;
      float nr = dinvIn[src] * dv;
      float2 xv = X2[(size_t)src * 192 + 128 + l];
      float2 rv = R2[typ * 64 + l];
      float px, py;
      if (l == 0) { px = xv.x * rv.x; py = xv.y * rv.y; }
      else { px = xv.x * rv.x + xv.y * rv.y; py = xv.x * rv.y - xv.y * rv.x; }
      cix += nr * px; ciy += nr * py;
    }
  }
  float cox = 0.f, coy = 0.f;
  {
    float dv = dinvOut[v];
    int b = offOut[v];
    int e = (v + 1 < N_ENT) ? offOut[v + 1] : EHALF;
    for (int i = b; i < e; ++i) {
      int pe = sortedOut[i];
      int src = pe & 131071, typ = pe >> 17;
      float nr = dinvOut[src] * dv;
      float2 xv = X2[(size_t)src * 192 + 128 + l];
      float2 rv = R2[typ * 64 + l];
      float px, py;
      if (l == 0) { px = xv.x * rv.x; py = xv.y * rv.y; }
      else { px = xv.x * rv.x + xv.y * rv.y; py = xv.x * rv.y - xv.y * rv.x; }
      cox += nr * px; coy += nr * py;
    }
  }
  A2[(size_t)v * 192 + l]      = make_float2(cix, ciy);
  A2[(size_t)v * 192 + 64 + l] = make_float2(cox, coy);
}

// ---------------- batch norm ----------------
__global__ void k_bnfin(const float* __restrict__ bnAcc, const float* __restrict__ bnw,
                        const float* __restrict__ bnb, float* __restrict__ ss) {
  int c = threadIdx.x;
  float mu = bnAcc[c] * (1.f / (float)N_ENT);
  float var = bnAcc[128 + c] * (1.f / (float)N_ENT) - mu * mu;
  float sc = bnw[c] * rsqrtf(var + 1e-5f);
  ss[c] = sc; ss[128 + c] = bnb[c] - mu * sc;
}

__global__ void k_norm(float* __restrict__ out, const float* __restrict__ ss) {
  int i = blockIdx.x * 256 + threadIdx.x;  // 3.2M float4s
  float4* o = (float4*)out;
  float4 v = o[i];
  int c = (i & 31) * 4;
  v.x = v.x * ss[c]     + ss[128 + c];
  v.y = v.y * ss[c + 1] + ss[129 + c];
  v.z = v.z * ss[c + 2] + ss[130 + c];
  v.w = v.w * ss[c + 3] + ss[131 + c];
  o[i] = v;
}

extern "C" void kernel_launch(void* const* d_in, const int* in_sizes, int n_in,
                              void* d_out, int out_size, void* d_ws, size_t ws_size,
                              hipStream_t stream) {
  const float* x       = (const float*)d_in[0];
  const float* rel     = (const float*)d_in[1];
  const float* w_in    = (const float*)d_in[2];
  const float* w_out   = (const float*)d_in[3];
  const float* w_loop  = (const float*)d_in[4];
  const float* w_rel   = (const float*)d_in[5];
  const float* looprel = (const float*)d_in[6];
  const float* bias    = (const float*)d_in[7];
  const float* bnw     = (const float*)d_in[8];
  const float* bnb     = (const float*)d_in[9];
  const int*   ei      = (const int*)d_in[10];
  const int*   et      = (const int*)d_in[11];
  float* out = (float*)d_out;

  char* p = (char*)d_ws;
  auto alloc = [&](size_t bytes) -> void* {
    void* r = (void*)p;
    p += (bytes + 255) & ~(size_t)255;
    return r;
  };
  float* Abuf    = (float*)alloc((size_t)N_ENT * 384 * 4);
  float* Wstack  = (float*)alloc(384 * 128 * 4);
  float* Ftab    = (float*)alloc(128 * 128 * 4);
  float* Gtab    = (float*)alloc(128 * 128 * 4);
  float* Rf      = (float*)alloc(501 * 128 * 4);
  int*   degIn   = (int*)alloc(N_ENT * 4);
  int*   degOut  = (int*)alloc(N_ENT * 4);
  float* dinvIn  = (float*)alloc(N_ENT * 4);
  float* dinvOut = (float*)alloc(N_ENT * 4);
  int*   cntIn   = (int*)alloc(N_ENT * 4);
  int*   cntOut  = (int*)alloc(N_ENT * 4);
  int*   offIn   = (int*)alloc(N_ENT * 4);
  int*   offOut  = (int*)alloc(N_ENT * 4);
  int*   curIn   = (int*)alloc(N_ENT * 4);
  int*   curOut  = (int*)alloc(N_ENT * 4);
  int*   partials= (int*)alloc(2 * 128 * 4);
  int*   sortedIn  = (int*)alloc(EHALF * 4);
  int*   sortedOut = (int*)alloc(EHALF * 4);
  float* bnAcc   = (float*)alloc(256 * 4);
  float* ss      = (float*)alloc(256 * 4);

  hipMemsetAsync(degIn, 0, N_ENT * 4, stream);
  hipMemsetAsync(degOut, 0, N_ENT * 4, stream);
  hipMemsetAsync(cntIn, 0, N_ENT * 4, stream);
  hipMemsetAsync(cntOut, 0, N_ENT * 4, stream);
  hipMemsetAsync(bnAcc, 0, 256 * 4, stream);

  // tables + relation spectra + folded weight stack
  k_tabs<<<64, 256, 0, stream>>>(Ftab, Gtab);
  k_dftrel<<<501, 128, 0, stream>>>(rel, looprel, Ftab, Rf);
  gemm128<<<2, 256, 0, stream>>>(Gtab, 128, w_in,   Wstack,             128, 128, 128, nullptr, nullptr);
  gemm128<<<2, 256, 0, stream>>>(Gtab, 128, w_out,  Wstack + 128 * 128, 128, 128, 128, nullptr, nullptr);
  gemm128<<<2, 256, 0, stream>>>(Gtab, 128, w_loop, Wstack + 256 * 128, 128, 128, 128, nullptr, nullptr);
  k_rotloop<<<64, 128, 0, stream>>>(Wstack + 256 * 128, Rf + 500 * 128);

  // Xf = rfft(x) into Abuf cols [256..384)
  gemm128<<<(N_ENT + 63) / 64, 256, 0, stream>>>(x, 128, Ftab, Abuf + 256, 384, N_ENT, 128, nullptr, nullptr);

  // degrees + counting sort of both edge halves by dst
  k_hist<<<(EHALF + 255) / 256, 256, 0, stream>>>(ei, degIn, cntIn, degOut, cntOut);
  k_dinv<<<(N_ENT + 255) / 256, 256, 0, stream>>>(degIn, dinvIn);
  k_dinv<<<(N_ENT + 255) / 256, 256, 0, stream>>>(degOut, dinvOut);
  const int NB = (N_ENT + 1023) / 1024;  // 98
  k_scan1<<<NB, 256, 0, stream>>>(cntIn, N_ENT, partials);
  k_scan2<<<1, 256, 0, stream>>>(partials, NB);
  k_scan3<<<NB, 256, 0, stream>>>(cntIn, N_ENT, partials, offIn);
  k_scan1<<<NB, 256, 0, stream>>>(cntOut, N_ENT, partials + 128);
  k_scan2<<<1, 256, 0, stream>>>(partials + 128, NB);
  k_scan3<<<NB, 256, 0, stream>>>(cntOut, N_ENT, partials + 128, offOut);
  hipMemcpyAsync(curIn, offIn, N_ENT * 4, hipMemcpyDeviceToDevice, stream);
  hipMemcpyAsync(curOut, offOut, N_ENT * 4, hipMemcpyDeviceToDevice, stream);
  k_scatter<<<(EHALF + 255) / 256, 256, 0, stream>>>(ei, et, curIn, curOut, sortedIn, sortedOut);

  // frequency-domain aggregation (writes c_in/c_out into Abuf)
  k_agg<<<N_ENT / 4, 256, 0, stream>>>(Abuf, Rf, sortedIn, offIn, dinvIn, sortedOut, offOut, dinvOut);

  // fused output GEMM: [c_in|c_out|Xf] @ [W~in;W~out;W~loop'] + bias, BN stats
  gemm128<<<(N_ENT + 63) / 64, 256, 0, stream>>>(Abuf, 384, Wstack, out, 128, N_ENT, 384, bias, bnAcc);
  k_bnfin<<<1, 128, 0, stream>>>(bnAcc, bnw, bnb, ss);
  k_norm<<<(N_ENT * 128 / 4) / 256, 256, 0, stream>>>(out, ss);

  // rel_out = rel_embed @ w_rel
  gemm128<<<(N_REL + 63) / 64, 256, 0, stream>>>(rel, 128, w_rel, out + (size_t)N_ENT * 128, 128, N_REL, 128, nullptr, nullptr);
}

// Round 2
// 643.236 us; speedup vs baseline: 1.3394x; 1.3394x over previous
//
#include <hip/hip_runtime.h>
#include <cmath>

#define N_ENT 100000
#define EHALF 1000000
#define N_REL 500

#ifndef M_PI
#define M_PI 3.14159265358979323846
#endif

typedef _Float16 f16x8 __attribute__((ext_vector_type(8)));
typedef _Float16 f16x2 __attribute__((ext_vector_type(2)));
typedef float f32x4 __attribute__((ext_vector_type(4)));

// ---------------- DFT tables ----------------
// Spectrum layout per row (128 floats): slot0=Re(bin0), slot1=Re(bin64),
// slot 2f=Re(bin f), slot 2f+1=Im(bin f) for f=1..63.
// Ftab[n][slot] fp32 (for Rf); FtabT[slot][n] fp16 (MFMA B^T operand).
// Gtab[slot][n]: spectrum @ (Gtab @ W) == irfft(spec) @ W, with 1/3 folded in.
__global__ void k_tabs(float* __restrict__ Ftab, float* __restrict__ Gtab,
                       _Float16* __restrict__ FtabT) {
  int i = blockIdx.x * 256 + threadIdx.x;
  if (i >= 128 * 128) return;
  int n = i >> 7, s = i & 127;
  float fv, gv;
  if (s == 0) { fv = 1.f; gv = 1.f / 384.f; }
  else if (s == 1) { float sg = (n & 1) ? -1.f : 1.f; fv = sg; gv = sg / 384.f; }
  else {
    int f = s >> 1;
    double ang = 2.0 * M_PI * (double)((f * n) & 127) / 128.0;
    if (!(s & 1)) { double c = cos(ang); fv = (float)c; gv = (float)(c * (2.0 / 384.0)); }
    else { double sv = sin(ang); fv = (float)(-sv); gv = (float)(-sv * (2.0 / 384.0)); }
  }
  Ftab[n * 128 + s] = fv;
  Gtab[s * 128 + n] = gv;
  FtabT[s * 128 + n] = (_Float16)fv;
}

// Rf[r] = spectrum of rel_all[r], r in [0,501); row 500 = loop_rel (fp32)
__global__ void k_dftrel(const float* __restrict__ rel, const float* __restrict__ looprel,
                         const float* __restrict__ Ftab, float* __restrict__ Rf) {
  int r = blockIdx.x, s = threadIdx.x;
  const float* row = (r < N_REL) ? rel + (size_t)r * 128 : looprel;
  float acc = 0.f;
  for (int n = 0; n < 128; ++n) acc += row[n] * Ftab[n * 128 + s];
  Rf[(size_t)r * 128 + s] = acc;
}

// Rotate Gw_loop rows by loop-rel spectrum (fp32, in place on Wstack rows 256..384)
__global__ void k_rotloop(float* __restrict__ Wl, const float* __restrict__ Rfl) {
  int c = threadIdx.x;  // 128
  int f = blockIdx.x;   // 0..63
  if (f == 0) {
    Wl[c]       = Rfl[0] * Wl[c];
    Wl[128 + c] = Rfl[1] * Wl[128 + c];
  } else {
    float rr = Rfl[2 * f], ri = Rfl[2 * f + 1];
    float a = Wl[2 * f * 128 + c], b = Wl[(2 * f + 1) * 128 + c];
    Wl[2 * f * 128 + c]       = rr * a + ri * b;
    Wl[(2 * f + 1) * 128 + c] = ri * a - rr * b;
  }
}

// fp32 [K][128] -> fp16 transposed [128][K]
__global__ void k_wt(const float* __restrict__ W, _Float16* __restrict__ WT, int K) {
  int i = blockIdx.x * 256 + threadIdx.x;
  if (i >= K * 128) return;
  int k = i >> 7, c = i & 127;
  WT[(size_t)c * K + k] = (_Float16)W[i];
}

// fp32 -> fp16 vector convert (8 elems/thread)
__global__ void k_cvt(const float* __restrict__ in, _Float16* __restrict__ outh, int n8) {
  int i = blockIdx.x * 256 + threadIdx.x;
  if (i >= n8) return;
  float4 a = ((const float4*)in)[2 * i], b = ((const float4*)in)[2 * i + 1];
  f16x8 h = {(_Float16)a.x, (_Float16)a.y, (_Float16)a.z, (_Float16)a.w,
             (_Float16)b.x, (_Float16)b.y, (_Float16)b.z, (_Float16)b.w};
  ((f16x8*)outh)[i] = h;
}

// ---------------- fp32 GEMM (small preps + rel_out), N fixed = 128 ----------------
__global__ __launch_bounds__(256) void gemm128(
    const float* __restrict__ A, int lda,
    const float* __restrict__ B,
    float* __restrict__ C, int ldc,
    int M, int K) {
  __shared__ float As[64][64];
  __shared__ float Bs[64][128];
  const int t = threadIdx.x;
  const int m0 = blockIdx.x * 64;
  const int cg = t & 31;
  const int eg = t >> 5;
  float acc[8][4];
#pragma unroll
  for (int i = 0; i < 8; ++i)
#pragma unroll
    for (int j = 0; j < 4; ++j) acc[i][j] = 0.f;

  for (int k0 = 0; k0 < K; k0 += 64) {
#pragma unroll
    for (int p = 0; p < 4; ++p) {
      int idx = t + p * 256;
      int r = idx >> 4, c4 = idx & 15;
      int gr = m0 + r;
      float4 v = make_float4(0.f, 0.f, 0.f, 0.f);
      if (gr < M) v = *(const float4*)(A + (size_t)gr * lda + k0 + c4 * 4);
      *(float4*)&As[r][c4 * 4] = v;
    }
#pragma unroll
    for (int p = 0; p < 8; ++p) {
      int idx = t + p * 256;
      int r = idx >> 5, c4 = idx & 31;
      float4 v = *(const float4*)(B + (size_t)(k0 + r) * 128 + c4 * 4);
      *(float4*)&Bs[r][c4 * 4] = v;
    }
    __syncthreads();
#pragma unroll
    for (int k = 0; k < 64; ++k) {
      float4 bv = *(float4*)&Bs[k][cg * 4];
#pragma unroll
      for (int i = 0; i < 8; ++i) {
        float av = As[eg * 8 + i][k];
        acc[i][0] += av * bv.x; acc[i][1] += av * bv.y;
        acc[i][2] += av * bv.z; acc[i][3] += av * bv.w;
      }
    }
    __syncthreads();
  }
#pragma unroll
  for (int i = 0; i < 8; ++i) {
    int gr = m0 + eg * 8 + i;
    if (gr < M) {
      float4 v = make_float4(acc[i][0], acc[i][1], acc[i][2], acc[i][3]);
      *(float4*)(C + (size_t)gr * ldc + cg * 4) = v;
    }
  }
}

// ---------------- f16 MFMA GEMM, N=128 ----------------
// A fp16 [M][lda]; BT fp16 [128][K] (B transposed); C fp32 or fp16 [M][ldc].
// Block: 256 thr = 4 waves, 64 rows/wave (4 MFMA row-tiles), full N=128 (8 col-tiles).
// BT staged in LDS in KS-wide K-slices, XOR-swizzled to kill bank conflicts.
template<int K, int KS, bool F16OUT, bool BN>
__global__ __launch_bounds__(256) void mgemm(
    const _Float16* __restrict__ A, int lda,
    const _Float16* __restrict__ BT,
    void* __restrict__ Cv, int ldc, int M,
    const float* __restrict__ bias, float* __restrict__ bnAcc) {
  __shared__ __align__(16) char lds[128 * KS * 2 + 4096];
  const int t = threadIdx.x;
  const int l = t & 63, w = t >> 6;
  const int col0 = l & 15, rg = l >> 4;
  const int rowbase = blockIdx.x * 256 + w * 64;
  const int sw = (col0 & 7) << 4;

  f32x4 acc[4][8];
  f32x4 zz = {0.f, 0.f, 0.f, 0.f};
#pragma unroll
  for (int a = 0; a < 4; ++a)
#pragma unroll
    for (int n = 0; n < 8; ++n) acc[a][n] = zz;

  for (int ks0 = 0; ks0 < K; ks0 += KS) {
    __syncthreads();
    const int CH = KS / 8;  // 16B chunks per BT row
    for (int u = t; u < 128 * CH; u += 256) {
      int col = u / CH, kc = u % CH;
      f16x8 vch = *(const f16x8*)(BT + (size_t)col * K + ks0 + kc * 8);
      *(f16x8*)(lds + col * (KS * 2) + ((kc * 16) ^ ((col & 7) << 4))) = vch;
    }
    __syncthreads();
#pragma unroll
    for (int ks = 0; ks < KS / 32; ++ks) {
      int kb = ks0 + ks * 32 + rg * 8;
      f16x8 af[4];
#pragma unroll
      for (int a = 0; a < 4; ++a) {
        int rb = rowbase + a * 16;
        if (rb < M) af[a] = *(const f16x8*)(A + (size_t)(rb + col0) * lda + kb);
        else af[a] = (f16x8){0, 0, 0, 0, 0, 0, 0, 0};
      }
      int kc = ks * 4 + rg;
#pragma unroll
      for (int n = 0; n < 8; ++n) {
        f16x8 bf = *(const f16x8*)(lds + (n * 16 + col0) * (KS * 2) + ((kc * 16) ^ sw));
#pragma unroll
        for (int a = 0; a < 4; ++a)
          acc[a][n] = __builtin_amdgcn_mfma_f32_16x16x32_f16(af[a], bf, acc[a][n], 0, 0, 0);
      }
    }
  }

  if (F16OUT) {
    _Float16* C = (_Float16*)Cv;
#pragma unroll
    for (int a = 0; a < 4; ++a) {
      int rb = rowbase + a * 16;
      if (rb >= M) continue;
#pragma unroll
      for (int n = 0; n < 8; ++n) {
        int col = n * 16 + col0;
#pragma unroll
        for (int r = 0; r < 4; ++r)
          C[(size_t)(rb + rg * 4 + r) * ldc + col] = (_Float16)acc[a][n][r];
      }
    }
  } else {
    float* C = (float*)Cv;
    float sacc[8], qacc[8];
#pragma unroll
    for (int n = 0; n < 8; ++n) { sacc[n] = 0.f; qacc[n] = 0.f; }
#pragma unroll
    for (int a = 0; a < 4; ++a) {
      int rb = rowbase + a * 16;
      if (rb >= M) continue;
#pragma unroll
      for (int n = 0; n < 8; ++n) {
        int col = n * 16 + col0;
        float bi = bias ? bias[col] : 0.f;
#pragma unroll
        for (int r = 0; r < 4; ++r) {
          float val = acc[a][n][r] + bi;
          C[(size_t)(rb + rg * 4 + r) * ldc + col] = val;
          if (BN) { sacc[n] += val; qacc[n] += val * val; }
        }
      }
    }
    if (BN) {
      __syncthreads();
      float* Sb = (float*)lds;
      float* Qb = Sb + 512;
#pragma unroll
      for (int n = 0; n < 8; ++n) {
        float s = sacc[n], q = qacc[n];
        s += __shfl_xor(s, 16); s += __shfl_xor(s, 32);
        q += __shfl_xor(q, 16); q += __shfl_xor(q, 32);
        if (rg == 0) { Sb[w * 128 + n * 16 + col0] = s; Qb[w * 128 + n * 16 + col0] = q; }
      }
      __syncthreads();
      if (t < 128) {
        float s = Sb[t] + Sb[128 + t] + Sb[256 + t] + Sb[384 + t];
        float q = Qb[t] + Qb[128 + t] + Qb[256 + t] + Qb[384 + t];
        atomicAdd(&bnAcc[t], s);
        atomicAdd(&bnAcc[128 + t], q);
      }
    }
  }
}

// ---------------- edge preprocessing ----------------
__global__ void k_hist(const int* __restrict__ ei,
                       int* degIn, int* cntIn, int* degOut, int* cntOut) {
  int e = blockIdx.x * 256 + threadIdx.x;
  if (e >= EHALF) return;
  atomicAdd(&degIn[ei[e]], 1);
  atomicAdd(&cntIn[ei[2 * EHALF + e]], 1);
  atomicAdd(&degOut[ei[EHALF + e]], 1);
  atomicAdd(&cntOut[ei[3 * EHALF + e]], 1);
}

__global__ void k_dinv(const int* __restrict__ deg, float* __restrict__ dinv) {
  int v = blockIdx.x * 256 + threadIdx.x;
  if (v >= N_ENT) return;
  int d = deg[v];
  dinv[v] = (d > 0) ? rsqrtf((float)d) : 0.f;
}

__global__ void k_scan1(const int* __restrict__ cnt, int n, int* __restrict__ partials) {
  __shared__ int sd[256];
  int base = blockIdx.x * 1024, t = threadIdx.x;
  int s = 0;
#pragma unroll
  for (int j = 0; j < 4; ++j) { int i = base + t * 4 + j; if (i < n) s += cnt[i]; }
  sd[t] = s; __syncthreads();
  for (int o = 128; o > 0; o >>= 1) { if (t < o) sd[t] += sd[t + o]; __syncthreads(); }
  if (t == 0) partials[blockIdx.x] = sd[0];
}

__global__ void k_scan2(int* __restrict__ partials, int nb) {
  __shared__ int sd[256];
  int t = threadIdx.x;
  int v = (t < nb) ? partials[t] : 0;
  sd[t] = v; __syncthreads();
  for (int o = 1; o < 256; o <<= 1) {
    int add = (t >= o) ? sd[t - o] : 0;
    __syncthreads();
    sd[t] += add;
    __syncthreads();
  }
  if (t < nb) partials[t] = sd[t] - v;
}

__global__ void k_scan3(const int* __restrict__ cnt, int n,
                        const int* __restrict__ partials, int* __restrict__ off) {
  __shared__ int sd[256];
  int base = blockIdx.x * 1024, t = threadIdx.x;
  int c[4]; int s = 0;
#pragma unroll
  for (int j = 0; j < 4; ++j) { int i = base + t * 4 + j; c[j] = (i < n) ? cnt[i] : 0; s += c[j]; }
  sd[t] = s; __syncthreads();
  for (int o = 1; o < 256; o <<= 1) {
    int add = (t >= o) ? sd[t - o] : 0;
    __syncthreads();
    sd[t] += add;
    __syncthreads();
  }
  int excl = sd[t] - s + partials[blockIdx.x];
#pragma unroll
  for (int j = 0; j < 4; ++j) { int i = base + t * 4 + j; if (i < n) off[i] = excl; excl += c[j]; }
}

__global__ void k_scatter(const int* __restrict__ ei, const int* __restrict__ et,
                          int* curIn, int* curOut,
                          int* __restrict__ sortedIn, int* __restrict__ sortedOut) {
  int e = blockIdx.x * 256 + threadIdx.x;
  if (e >= EHALF) return;
  {
    int src = ei[e], dst = ei[2 * EHALF + e], typ = et[e];
    int pos = atomicAdd(&curIn[dst], 1);
    sortedIn[pos] = src | (typ << 17);
  }
  {
    int src = ei[EHALF + e], dst = ei[3 * EHALF + e], typ = et[EHALF + e];
    int pos = atomicAdd(&curOut[dst], 1);
    sortedOut[pos] = src | (typ << 17);
  }
}

// ---------------- frequency-domain edge aggregation (fp16 spectra) ----------------
// Abuf_h row v (384 halfs): [c_in 128 | c_out 128 | Xf 128]. Wave per entity;
// lane l owns complex bin l (lane 0: the two real bins 0/64). Rf stays fp32.
__global__ __launch_bounds__(256) void k_agg(
    _Float16* __restrict__ Abuf, const float* __restrict__ Rf,
    const int* __restrict__ sortedIn, const int* __restrict__ offIn, const float* __restrict__ dinvIn,
    const int* __restrict__ sortedOut, const int* __restrict__ offOut, const float* __restrict__ dinvOut) {
  int w = threadIdx.x >> 6, l = threadIdx.x & 63;
  int v = blockIdx.x * 4 + w;
  const float2* R2 = (const float2*)Rf;

  float cix = 0.f, ciy = 0.f, cox = 0.f, coy = 0.f;
  {
    float dv = dinvIn[v];
    int b = offIn[v];
    int e = (v + 1 < N_ENT) ? offIn[v + 1] : EHALF;
    int i = b;
    for (; i + 2 <= e; i += 2) {
      int pe0 = sortedIn[i], pe1 = sortedIn[i + 1];
      int s0 = pe0 & 131071, t0 = pe0 >> 17;
      int s1 = pe1 & 131071, t1 = pe1 >> 17;
      f16x2 x0 = ((const f16x2*)(Abuf + (size_t)s0 * 384 + 256))[l];
      f16x2 x1 = ((const f16x2*)(Abuf + (size_t)s1 * 384 + 256))[l];
      float2 r0 = R2[t0 * 64 + l];
      float2 r1 = R2[t1 * 64 + l];
      float n0 = dinvIn[s0] * dv, n1 = dinvIn[s1] * dv;
      float x0r = (float)x0[0], x0i = (float)x0[1];
      float x1r = (float)x1[0], x1i = (float)x1[1];
      float p0x, p0y, p1x, p1y;
      if (l == 0) {
        p0x = x0r * r0.x; p0y = x0i * r0.y;
        p1x = x1r * r1.x; p1y = x1i * r1.y;
      } else {
        p0x = x0r * r0.x + x0i * r0.y; p0y = x0r * r0.y - x0i * r0.x;
        p1x = x1r * r1.x + x1i * r1.y; p1y = x1r * r1.y - x1i * r1.x;
      }
      cix += n0 * p0x + n1 * p1x; ciy += n0 * p0y + n1 * p1y;
    }
    if (i < e) {
      int pe = sortedIn[i];
      int s0 = pe & 131071, t0 = pe >> 17;
      f16x2 x0 = ((const f16x2*)(Abuf + (size_t)s0 * 384 + 256))[l];
      float2 r0 = R2[t0 * 64 + l];
      float n0 = dinvIn[s0] * dv;
      float x0r = (float)x0[0], x0i = (float)x0[1];
      float px, py;
      if (l == 0) { px = x0r * r0.x; py = x0i * r0.y; }
      else { px = x0r * r0.x + x0i * r0.y; py = x0r * r0.y - x0i * r0.x; }
      cix += n0 * px; ciy += n0 * py;
    }
  }
  {
    float dv = dinvOut[v];
    int b = offOut[v];
    int e = (v + 1 < N_ENT) ? offOut[v + 1] : EHALF;
    int i = b;
    for (; i + 2 <= e; i += 2) {
      int pe0 = sortedOut[i], pe1 = sortedOut[i + 1];
      int s0 = pe0 & 131071, t0 = pe0 >> 17;
      int s1 = pe1 & 131071, t1 = pe1 >> 17;
      f16x2 x0 = ((const f16x2*)(Abuf + (size_t)s0 * 384 + 256))[l];
      f16x2 x1 = ((const f16x2*)(Abuf + (size_t)s1 * 384 + 256))[l];
      float2 r0 = R2[t0 * 64 + l];
      float2 r1 = R2[t1 * 64 + l];
      float n0 = dinvOut[s0] * dv, n1 = dinvOut[s1] * dv;
      float x0r = (float)x0[0], x0i = (float)x0[1];
      float x1r = (float)x1[0], x1i = (float)x1[1];
      float p0x, p0y, p1x, p1y;
      if (l == 0) {
        p0x = x0r * r0.x; p0y = x0i * r0.y;
        p1x = x1r * r1.x; p1y = x1i * r1.y;
      } else {
        p0x = x0r * r0.x + x0i * r0.y; p0y = x0r * r0.y - x0i * r0.x;
        p1x = x1r * r1.x + x1i * r1.y; p1y = x1r * r1.y - x1i * r1.x;
      }
      cox += n0 * p0x + n1 * p1x; coy += n0 * p0y + n1 * p1y;
    }
    if (i < e) {
      int pe = sortedOut[i];
      int s0 = pe & 131071, t0 = pe >> 17;
      f16x2 x0 = ((const f16x2*)(Abuf + (size_t)s0 * 384 + 256))[l];
      float2 r0 = R2[t0 * 64 + l];
      float n0 = dinvOut[s0] * dv;
      float x0r = (float)x0[0], x0i = (float)x0[1];
      float px, py;
      if (l == 0) { px = x0r * r0.x; py = x0i * r0.y; }
      else { px = x0r * r0.x + x0i * r0.y; py = x0r * r0.y - x0i * r0.x; }
      cox += n0 * px; coy += n0 * py;
    }
  }
  ((f16x2*)(Abuf + (size_t)v * 384))[l]       = (f16x2){(_Float16)cix, (_Float16)ciy};
  ((f16x2*)(Abuf + (size_t)v * 384 + 128))[l] = (f16x2){(_Float16)cox, (_Float16)coy};
}

// ---------------- batch norm ----------------
__global__ void k_bnfin(const float* __restrict__ bnAcc, const float* __restrict__ bnw,
                        const float* __restrict__ bnb, float* __restrict__ ss) {
  int c = threadIdx.x;
  float mu = bnAcc[c] * (1.f / (float)N_ENT);
  float var = bnAcc[128 + c] * (1.f / (float)N_ENT) - mu * mu;
  float sc = bnw[c] * rsqrtf(var + 1e-5f);
  ss[c] = sc; ss[128 + c] = bnb[c] - mu * sc;
}

__global__ void k_norm(float* __restrict__ out, const float* __restrict__ ss) {
  int i = blockIdx.x * 256 + threadIdx.x;
  float4* o = (float4*)out;
  float4 v = o[i];
  int c = (i & 31) * 4;
  v.x = v.x * ss[c]     + ss[128 + c];
  v.y = v.y * ss[c + 1] + ss[129 + c];
  v.z = v.z * ss[c + 2] + ss[130 + c];
  v.w = v.w * ss[c + 3] + ss[131 + c];
  o[i] = v;
}

extern "C" void kernel_launch(void* const* d_in, const int* in_sizes, int n_in,
                              void* d_out, int out_size, void* d_ws, size_t ws_size,
                              hipStream_t stream) {
  const float* x       = (const float*)d_in[0];
  const float* rel     = (const float*)d_in[1];
  const float* w_in    = (const float*)d_in[2];
  const float* w_out   = (const float*)d_in[3];
  const float* w_loop  = (const float*)d_in[4];
  const float* w_rel   = (const float*)d_in[5];
  const float* looprel = (const float*)d_in[6];
  const float* bias    = (const float*)d_in[7];
  const float* bnw     = (const float*)d_in[8];
  const float* bnb     = (const float*)d_in[9];
  const int*   ei      = (const int*)d_in[10];
  const int*   et      = (const int*)d_in[11];
  float* out = (float*)d_out;

  char* p = (char*)d_ws;
  auto alloc = [&](size_t bytes) -> void* {
    void* r = (void*)p;
    p += (bytes + 255) & ~(size_t)255;
    return r;
  };
  _Float16* Abuf  = (_Float16*)alloc((size_t)N_ENT * 384 * 2);
  _Float16* xh    = (_Float16*)alloc((size_t)N_ENT * 128 * 2);
  _Float16* WT    = (_Float16*)alloc(128 * 384 * 2);
  _Float16* FtabT = (_Float16*)alloc(128 * 128 * 2);
  float* Wstack   = (float*)alloc(384 * 128 * 4);
  float* Ftab     = (float*)alloc(128 * 128 * 4);
  float* Gtab     = (float*)alloc(128 * 128 * 4);
  float* Rf       = (float*)alloc(501 * 128 * 4);
  int*   degIn    = (int*)alloc(N_ENT * 4);
  int*   degOut   = (int*)alloc(N_ENT * 4);
  float* dinvIn   = (float*)alloc(N_ENT * 4);
  float* dinvOut  = (float*)alloc(N_ENT * 4);
  int*   cntIn    = (int*)alloc(N_ENT * 4);
  int*   cntOut   = (int*)alloc(N_ENT * 4);
  int*   offIn    = (int*)alloc(N_ENT * 4);
  int*   offOut   = (int*)alloc(N_ENT * 4);
  int*   curIn    = (int*)alloc(N_ENT * 4);
  int*   curOut   = (int*)alloc(N_ENT * 4);
  int*   partials = (int*)alloc(2 * 128 * 4);
  int*   sortedIn  = (int*)alloc(EHALF * 4);
  int*   sortedOut = (int*)alloc(EHALF * 4);
  float* bnAcc    = (float*)alloc(256 * 4);
  float* ss       = (float*)alloc(256 * 4);

  hipMemsetAsync(degIn, 0, N_ENT * 4, stream);
  hipMemsetAsync(degOut, 0, N_ENT * 4, stream);
  hipMemsetAsync(cntIn, 0, N_ENT * 4, stream);
  hipMemsetAsync(cntOut, 0, N_ENT * 4, stream);
  hipMemsetAsync(bnAcc, 0, 256 * 4, stream);

  // tables + relation spectra + folded weight stack
  k_tabs<<<64, 256, 0, stream>>>(Ftab, Gtab, FtabT);
  k_dftrel<<<501, 128, 0, stream>>>(rel, looprel, Ftab, Rf);
  gemm128<<<2, 256, 0, stream>>>(Gtab, 128, w_in,   Wstack,             128, 128, 128);
  gemm128<<<2, 256, 0, stream>>>(Gtab, 128, w_out,  Wstack + 128 * 128, 128, 128, 128);
  gemm128<<<2, 256, 0, stream>>>(Gtab, 128, w_loop, Wstack + 256 * 128, 128, 128, 128);
  k_rotloop<<<64, 128, 0, stream>>>(Wstack + 256 * 128, Rf + 500 * 128);
  k_wt<<<192, 256, 0, stream>>>(Wstack, WT, 384);

  // x -> fp16; Xf = rfft(x) (f16 MFMA) into Abuf cols [256..384)
  k_cvt<<<6250, 256, 0, stream>>>(x, xh, N_ENT * 128 / 8);
  mgemm<128, 128, true, false><<<(N_ENT + 255) / 256, 256, 0, stream>>>(
      xh, 128, FtabT, (void*)(Abuf + 256), 384, N_ENT, nullptr, nullptr);

  // degrees + counting sort of both edge halves by dst
  k_hist<<<(EHALF + 255) / 256, 256, 0, stream>>>(ei, degIn, cntIn, degOut, cntOut);
  k_dinv<<<(N_ENT + 255) / 256, 256, 0, stream>>>(degIn, dinvIn);
  k_dinv<<<(N_ENT + 255) / 256, 256, 0, stream>>>(degOut, dinvOut);
  const int NB = (N_ENT + 1023) / 1024;
  k_scan1<<<NB, 256, 0, stream>>>(cntIn, N_ENT, partials);
  k_scan2<<<1, 256, 0, stream>>>(partials, NB);
  k_scan3<<<NB, 256, 0, stream>>>(cntIn, N_ENT, partials, offIn);
  k_scan1<<<NB, 256, 0, stream>>>(cntOut, N_ENT, partials + 128);
  k_scan2<<<1, 256, 0, stream>>>(partials + 128, NB);
  k_scan3<<<NB, 256, 0, stream>>>(cntOut, N_ENT, partials + 128, offOut);
  hipMemcpyAsync(curIn, offIn, N_ENT * 4, hipMemcpyDeviceToDevice, stream);
  hipMemcpyAsync(curOut, offOut, N_ENT * 4, hipMemcpyDeviceToDevice, stream);
  k_scatter<<<(EHALF + 255) / 256, 256, 0, stream>>>(ei, et, curIn, curOut, sortedIn, sortedOut);

  // frequency-domain aggregation (fp16 spectra)
  k_agg<<<N_ENT / 4, 256, 0, stream>>>(Abuf, Rf, sortedIn, offIn, dinvIn, sortedOut, offOut, dinvOut);

  // fused output GEMM (f16 MFMA): [c_in|c_out|Xf] @ Wstack + bias, BN stats
  mgemm<384, 192, false, true><<<(N_ENT + 255) / 256, 256, 0, stream>>>(
      Abuf, 384, WT, (void*)out, 128, N_ENT, bias, bnAcc);
  k_bnfin<<<1, 128, 0, stream>>>(bnAcc, bnw, bnb, ss);
  k_norm<<<(N_ENT * 128 / 4) / 256, 256, 0, stream>>>(out, ss);

  // rel_out = rel_embed @ w_rel (fp32)
  gemm128<<<(N_REL + 63) / 64, 256, 0, stream>>>(rel, 128, w_rel, out + (size_t)N_ENT * 128, 128, N_REL, 128);
}

// Round 3
// 454.208 us; speedup vs baseline: 1.8969x; 1.4162x over previous
//
#include <hip/hip_runtime.h>
#include <cmath>

#define N_ENT 100000
#define EHALF 1000000
#define N_REL 500
#define NBUK 196          // ceil(100000/512) coarse dst-buckets
#define DPB 512           // dsts per bucket (dst>>9)

#ifndef M_PI
#define M_PI 3.14159265358979323846
#endif

typedef _Float16 f16x8 __attribute__((ext_vector_type(8)));
typedef _Float16 f16x2 __attribute__((ext_vector_type(2)));
typedef float f32x4 __attribute__((ext_vector_type(4)));

union H16 { unsigned short u; _Float16 h; };

// ---------------- DFT tables ----------------
// Spectrum layout per row (128): slot0=Re(bin0), slot1=Re(bin64),
// slot 2f=Re(bin f), slot 2f+1=Im(bin f), f=1..63.
__global__ void k_tabs(float* __restrict__ Ftab, float* __restrict__ Gtab,
                       _Float16* __restrict__ FtabT) {
  int i = blockIdx.x * 256 + threadIdx.x;
  if (i >= 128 * 128) return;
  int n = i >> 7, s = i & 127;
  float fv, gv;
  if (s == 0) { fv = 1.f; gv = 1.f / 384.f; }
  else if (s == 1) { float sg = (n & 1) ? -1.f : 1.f; fv = sg; gv = sg / 384.f; }
  else {
    int f = s >> 1;
    double ang = 2.0 * M_PI * (double)((f * n) & 127) / 128.0;
    if (!(s & 1)) { double c = cos(ang); fv = (float)c; gv = (float)(c * (2.0 / 384.0)); }
    else { double sv = sin(ang); fv = (float)(-sv); gv = (float)(-sv * (2.0 / 384.0)); }
  }
  Ftab[n * 128 + s] = fv;
  Gtab[s * 128 + n] = gv;
  FtabT[s * 128 + n] = (_Float16)fv;
}

__global__ void k_dftrel(const float* __restrict__ rel, const float* __restrict__ looprel,
                         const float* __restrict__ Ftab, float* __restrict__ Rf) {
  int r = blockIdx.x, s = threadIdx.x;
  const float* row = (r < N_REL) ? rel + (size_t)r * 128 : looprel;
  float acc = 0.f;
  for (int n = 0; n < 128; ++n) acc += row[n] * Ftab[n * 128 + s];
  Rf[(size_t)r * 128 + s] = acc;
}

__global__ void k_rotloop(float* __restrict__ Wl, const float* __restrict__ Rfl) {
  int c = threadIdx.x;
  int f = blockIdx.x;
  if (f == 0) {
    Wl[c]       = Rfl[0] * Wl[c];
    Wl[128 + c] = Rfl[1] * Wl[128 + c];
  } else {
    float rr = Rfl[2 * f], ri = Rfl[2 * f + 1];
    float a = Wl[2 * f * 128 + c], b = Wl[(2 * f + 1) * 128 + c];
    Wl[2 * f * 128 + c]       = rr * a + ri * b;
    Wl[(2 * f + 1) * 128 + c] = ri * a - rr * b;
  }
}

__global__ void k_wt(const float* __restrict__ W, _Float16* __restrict__ WT, int K) {
  int i = blockIdx.x * 256 + threadIdx.x;
  if (i >= K * 128) return;
  int k = i >> 7, c = i & 127;
  WT[(size_t)c * K + k] = (_Float16)W[i];
}

// ---------------- fp32 GEMM (small preps + rel_out), N fixed = 128 ----------------
__global__ __launch_bounds__(256) void gemm128(
    const float* __restrict__ A, int lda,
    const float* __restrict__ B,
    float* __restrict__ C, int ldc,
    int M, int K) {
  __shared__ float As[64][64];
  __shared__ float Bs[64][128];
  const int t = threadIdx.x;
  const int m0 = blockIdx.x * 64;
  const int cg = t & 31;
  const int eg = t >> 5;
  float acc[8][4];
#pragma unroll
  for (int i = 0; i < 8; ++i)
#pragma unroll
    for (int j = 0; j < 4; ++j) acc[i][j] = 0.f;

  for (int k0 = 0; k0 < K; k0 += 64) {
#pragma unroll
    for (int p = 0; p < 4; ++p) {
      int idx = t + p * 256;
      int r = idx >> 4, c4 = idx & 15;
      int gr = m0 + r;
      float4 v = make_float4(0.f, 0.f, 0.f, 0.f);
      if (gr < M) v = *(const float4*)(A + (size_t)gr * lda + k0 + c4 * 4);
      *(float4*)&As[r][c4 * 4] = v;
    }
#pragma unroll
    for (int p = 0; p < 8; ++p) {
      int idx = t + p * 256;
      int r = idx >> 5, c4 = idx & 31;
      float4 v = *(const float4*)(B + (size_t)(k0 + r) * 128 + c4 * 4);
      *(float4*)&Bs[r][c4 * 4] = v;
    }
    __syncthreads();
#pragma unroll
    for (int k = 0; k < 64; ++k) {
      float4 bv = *(float4*)&Bs[k][cg * 4];
#pragma unroll
      for (int i = 0; i < 8; ++i) {
        float av = As[eg * 8 + i][k];
        acc[i][0] += av * bv.x; acc[i][1] += av * bv.y;
        acc[i][2] += av * bv.z; acc[i][3] += av * bv.w;
      }
    }
    __syncthreads();
  }
#pragma unroll
  for (int i = 0; i < 8; ++i) {
    int gr = m0 + eg * 8 + i;
    if (gr < M) {
      float4 v = make_float4(acc[i][0], acc[i][1], acc[i][2], acc[i][3]);
      *(float4*)(C + (size_t)gr * ldc + cg * 4) = v;
    }
  }
}

// ---------------- f16 MFMA GEMM, N=128 ----------------
__device__ inline f16x8 loadAfrag(const _Float16* A, size_t off) {
  return *(const f16x8*)(A + off);
}
__device__ inline f16x8 loadAfrag(const float* A, size_t off) {
  float4 u = *(const float4*)(A + off);
  float4 v = *(const float4*)(A + off + 4);
  return (f16x8){(_Float16)u.x, (_Float16)u.y, (_Float16)u.z, (_Float16)u.w,
                 (_Float16)v.x, (_Float16)v.y, (_Float16)v.z, (_Float16)v.w};
}

template<int K, int KS, bool F16OUT, bool BN, typename AT>
__global__ __launch_bounds__(256) void mgemm(
    const AT* __restrict__ A, int lda,
    const _Float16* __restrict__ BT,
    void* __restrict__ Cv, int ldc, int M,
    const float* __restrict__ bias, float* __restrict__ bnAcc) {
  __shared__ __align__(16) char lds[128 * KS * 2 + 4096];
  const int t = threadIdx.x;
  const int l = t & 63, w = t >> 6;
  const int col0 = l & 15, rg = l >> 4;
  const int rowbase = blockIdx.x * 256 + w * 64;
  const int sw = (col0 & 7) << 4;

  f32x4 acc[4][8];
  f32x4 zz = {0.f, 0.f, 0.f, 0.f};
#pragma unroll
  for (int a = 0; a < 4; ++a)
#pragma unroll
    for (int n = 0; n < 8; ++n) acc[a][n] = zz;

  for (int ks0 = 0; ks0 < K; ks0 += KS) {
    __syncthreads();
    const int CH = KS / 8;
    for (int u = t; u < 128 * CH; u += 256) {
      int col = u / CH, kc = u % CH;
      f16x8 vch = *(const f16x8*)(BT + (size_t)col * K + ks0 + kc * 8);
      *(f16x8*)(lds + col * (KS * 2) + ((kc * 16) ^ ((col & 7) << 4))) = vch;
    }
    __syncthreads();
#pragma unroll
    for (int ks = 0; ks < KS / 32; ++ks) {
      int kb = ks0 + ks * 32 + rg * 8;
      f16x8 af[4];
#pragma unroll
      for (int a = 0; a < 4; ++a) {
        int rb = rowbase + a * 16;
        if (rb < M) af[a] = loadAfrag(A, (size_t)(rb + col0) * lda + kb);
        else af[a] = (f16x8){0, 0, 0, 0, 0, 0, 0, 0};
      }
      int kc = ks * 4 + rg;
#pragma unroll
      for (int n = 0; n < 8; ++n) {
        f16x8 bf = *(const f16x8*)(lds + (n * 16 + col0) * (KS * 2) + ((kc * 16) ^ sw));
#pragma unroll
        for (int a = 0; a < 4; ++a)
          acc[a][n] = __builtin_amdgcn_mfma_f32_16x16x32_f16(af[a], bf, acc[a][n], 0, 0, 0);
      }
    }
  }

  if (F16OUT) {
    _Float16* C = (_Float16*)Cv;
#pragma unroll
    for (int a = 0; a < 4; ++a) {
      int rb = rowbase + a * 16;
      if (rb >= M) continue;
#pragma unroll
      for (int n = 0; n < 8; ++n) {
        int col = n * 16 + col0;
#pragma unroll
        for (int r = 0; r < 4; ++r)
          C[(size_t)(rb + rg * 4 + r) * ldc + col] = (_Float16)acc[a][n][r];
      }
    }
  } else {
    float* C = (float*)Cv;
    float sacc[8], qacc[8];
#pragma unroll
    for (int n = 0; n < 8; ++n) { sacc[n] = 0.f; qacc[n] = 0.f; }
#pragma unroll
    for (int a = 0; a < 4; ++a) {
      int rb = rowbase + a * 16;
      if (rb >= M) continue;
#pragma unroll
      for (int n = 0; n < 8; ++n) {
        int col = n * 16 + col0;
        float bi = bias ? bias[col] : 0.f;
#pragma unroll
        for (int r = 0; r < 4; ++r) {
          float val = acc[a][n][r] + bi;
          C[(size_t)(rb + rg * 4 + r) * ldc + col] = val;
          if (BN) { sacc[n] += val; qacc[n] += val * val; }
        }
      }
    }
    if (BN) {
      __syncthreads();
      float* Sb = (float*)lds;
      float* Qb = Sb + 512;
#pragma unroll
      for (int n = 0; n < 8; ++n) {
        float s = sacc[n], q = qacc[n];
        s += __shfl_xor(s, 16); s += __shfl_xor(s, 32);
        q += __shfl_xor(q, 16); q += __shfl_xor(q, 32);
        if (rg == 0) { Sb[w * 128 + n * 16 + col0] = s; Qb[w * 128 + n * 16 + col0] = q; }
      }
      __syncthreads();
      if (t < 128) {
        float s = Sb[t] + Sb[128 + t] + Sb[256 + t] + Sb[384 + t];
        float q = Qb[t] + Qb[128 + t] + Qb[256 + t] + Qb[384 + t];
        atomicAdd(&bnAcc[t], s);
        atomicAdd(&bnAcc[128 + t], q);
      }
    }
  }
}

// ---------------- edge preprocessing ----------------
// degrees (global atomics) + coarse bucket counts (LDS-privatized)
__global__ __launch_bounds__(256) void k_hist(const int* __restrict__ ei,
                       int* __restrict__ degIn, int* __restrict__ degOut,
                       int* __restrict__ bcntIn, int* __restrict__ bcntOut) {
  __shared__ int lbIn[NBUK], lbOut[NBUK];
  int t = threadIdx.x;
  if (t < NBUK) { lbIn[t] = 0; lbOut[t] = 0; }
  __syncthreads();
  int stride = gridDim.x * 256;
  for (int e = blockIdx.x * 256 + t; e < EHALF; e += stride) {
    atomicAdd(&degIn[ei[e]], 1);
    atomicAdd(&degOut[ei[EHALF + e]], 1);
    atomicAdd(&lbIn[ei[2 * EHALF + e] >> 9], 1);
    atomicAdd(&lbOut[ei[3 * EHALF + e] >> 9], 1);
  }
  __syncthreads();
  if (t < NBUK) {
    atomicAdd(&bcntIn[t], lbIn[t]);
    atomicAdd(&bcntOut[t], lbOut[t]);
  }
}

__global__ void k_dinv2(const int* __restrict__ degIn, const int* __restrict__ degOut,
                        float* __restrict__ dinvIn, float* __restrict__ dinvOut) {
  int i = blockIdx.x * 256 + threadIdx.x;
  if (i < N_ENT) {
    int d = degIn[i];
    dinvIn[i] = (d > 0) ? rsqrtf((float)d) : 0.f;
  } else if (i < 2 * N_ENT) {
    int j = i - N_ENT;
    int d = degOut[j];
    dinvOut[j] = (d > 0) ? rsqrtf((float)d) : 0.f;
  }
}

// scans of bucket counts: padded regions (coarse rec arrays) + exact (CSR)
__global__ void k_bscan(const int* __restrict__ bcntIn, const int* __restrict__ bcntOut,
                        int* __restrict__ boffIn, int* __restrict__ gcurIn, int* __restrict__ csrBIn,
                        int* __restrict__ boffOut, int* __restrict__ gcurOut, int* __restrict__ csrBOut,
                        int* __restrict__ offFineIn, int* __restrict__ offFineOut) {
  __shared__ int sp[256], se[256];
  int t = threadIdx.x;
  for (int dir = 0; dir < 2; ++dir) {
    const int* bc = dir ? bcntOut : bcntIn;
    int c = (t < NBUK) ? bc[t] : 0;
    int pv = (t < NBUK) ? ((c + 771) & ~3) : 0;  // region: cnt + up-to-768 pad, 32B-aligned
    sp[t] = pv; se[t] = c;
    __syncthreads();
    for (int o = 1; o < 256; o <<= 1) {
      int ap = (t >= o) ? sp[t - o] : 0;
      int ae = (t >= o) ? se[t - o] : 0;
      __syncthreads();
      sp[t] += ap; se[t] += ae;
      __syncthreads();
    }
    if (t < NBUK) {
      int exP = sp[t] - pv;
      int exE = se[t] - c;
      if (dir) { boffOut[t] = exP; gcurOut[t] = exP; csrBOut[t] = exE; }
      else     { boffIn[t]  = exP; gcurIn[t]  = exP; csrBIn[t]  = exE; }
    }
    __syncthreads();
  }
  if (t == 0) { offFineIn[N_ENT] = EHALF; offFineOut[N_ENT] = EHALF; }
}

// coarse split: block-exclusive padded 32B chunks per bucket -> no write amp
__global__ __launch_bounds__(256) void k_split(
    const int* __restrict__ srcA, const int* __restrict__ dstA, const int* __restrict__ typA,
    const float* __restrict__ dinv, int* __restrict__ gcur, uint2* __restrict__ rec) {
  __shared__ int bcnt[NBUK], cnt2[NBUK], base[NBUK], nn[NBUK];
  const int t = threadIdx.x;
  const int SPAN = 3907;  // 256 blocks * 3907 >= 1M
  int st = blockIdx.x * SPAN;
  int en = min(st + SPAN, EHALF);
  if (t < NBUK) { bcnt[t] = 0; cnt2[t] = 0; }
  __syncthreads();
  unsigned w0[16], w1[16]; int bb[16];
#pragma unroll
  for (int j = 0; j < 16; ++j) {
    int e = st + j * 256 + t;
    bb[j] = -1;
    if (e < en) {
      int s = srcA[e], d = dstA[e], ty = typA[e];
      float nm = dinv[s] * dinv[d];
      H16 cv; cv.h = (_Float16)nm;
      w0[j] = (unsigned)s | ((unsigned)ty << 17);
      w1[j] = (unsigned)(d & 511) | ((unsigned)cv.u << 16);
      int b = d >> 9;
      bb[j] = b;
      atomicAdd(&bcnt[b], 1);
    }
  }
  __syncthreads();
  if (t < NBUK) {
    int n = bcnt[t]; nn[t] = n;
    base[t] = n ? atomicAdd(&gcur[t], (n + 3) & ~3) : 0;
  }
  __syncthreads();
#pragma unroll
  for (int j = 0; j < 16; ++j) {
    if (bb[j] >= 0) {
      int p = atomicAdd(&cnt2[bb[j]], 1);
      rec[(size_t)base[bb[j]] + p] = make_uint2(w0[j], w1[j]);
    }
  }
  __syncthreads();
  if (t < NBUK) {
    int n = nn[t];
    if (n & 3) {
      int pe = (n + 3) & ~3;
      for (int k = n; k < pe; ++k) rec[(size_t)base[t] + k] = make_uint2(0u, 0u);
    }
  }
}

// fine sort within bucket -> dense CSR segment + per-dst offsets
__global__ __launch_bounds__(512) void k_fsort(
    const uint2* __restrict__ recIn, const int* __restrict__ boffIn, const int* __restrict__ gcurIn,
    const int* __restrict__ csrBIn, uint2* __restrict__ csrIn, int* __restrict__ offFineIn,
    const uint2* __restrict__ recOut, const int* __restrict__ boffOut, const int* __restrict__ gcurOut,
    const int* __restrict__ csrBOut, uint2* __restrict__ csrOut, int* __restrict__ offFineOut) {
  int b = blockIdx.x % NBUK;
  int dir = blockIdx.x / NBUK;
  const uint2* rec = dir ? recOut : recIn;
  const int gs = (dir ? boffOut : boffIn)[b];
  const int ge = (dir ? gcurOut : gcurIn)[b];
  const int cbase = (dir ? csrBOut : csrBIn)[b];
  uint2* csr = dir ? csrOut : csrIn;
  int* offF = dir ? offFineOut : offFineIn;
  __shared__ int h[DPB], sc[DPB], c2[DPB];
  int t = threadIdx.x;
  h[t] = 0; c2[t] = 0;
  __syncthreads();
  for (int i = gs + t; i < ge; i += 512) {
    uint2 r = rec[i];
    if (r.y >> 16) atomicAdd(&h[r.y & 511], 1);
  }
  __syncthreads();
  sc[t] = h[t];
  __syncthreads();
  for (int o = 1; o < 512; o <<= 1) {
    int a = (t >= o) ? sc[t - o] : 0;
    __syncthreads();
    sc[t] += a;
    __syncthreads();
  }
  int excl = sc[t] - h[t];
  int dst = b * 512 + t;
  if (dst < N_ENT) offF[dst] = cbase + excl;
  __syncthreads();
  sc[t] = excl;
  __syncthreads();
  for (int i = gs + t; i < ge; i += 512) {
    uint2 r = rec[i];
    if (r.y >> 16) {
      int d = r.y & 511;
      int p = atomicAdd(&c2[d], 1);
      csr[(size_t)cbase + sc[d] + p] = r;
    }
  }
}

// ---------------- frequency-domain edge aggregation (fp16 spectra) ----------------
__device__ inline void aggdir(const uint2* __restrict__ csr, int bgn, int end, int l,
                              const _Float16* __restrict__ Abuf, const float2* __restrict__ R2,
                              float& ax, float& ay) {
  int i = bgn;
  for (; i + 2 <= end; i += 2) {
    uint2 r0 = csr[i], r1 = csr[i + 1];
    int s0 = r0.x & 0x1FFFF, t0 = r0.x >> 17;
    int s1 = r1.x & 0x1FFFF, t1 = r1.x >> 17;
    H16 c0, c1; c0.u = (unsigned short)(r0.y >> 16); c1.u = (unsigned short)(r1.y >> 16);
    float n0 = (float)c0.h, n1 = (float)c1.h;
    f16x2 x0 = ((const f16x2*)(Abuf + (size_t)s0 * 384 + 256))[l];
    f16x2 x1 = ((const f16x2*)(Abuf + (size_t)s1 * 384 + 256))[l];
    float2 r0v = R2[t0 * 64 + l];
    float2 r1v = R2[t1 * 64 + l];
    float x0r = (float)x0[0], x0i = (float)x0[1];
    float x1r = (float)x1[0], x1i = (float)x1[1];
    float p0x, p0y, p1x, p1y;
    if (l == 0) {
      p0x = x0r * r0v.x; p0y = x0i * r0v.y;
      p1x = x1r * r1v.x; p1y = x1i * r1v.y;
    } else {
      p0x = x0r * r0v.x + x0i * r0v.y; p0y = x0r * r0v.y - x0i * r0v.x;
      p1x = x1r * r1v.x + x1i * r1v.y; p1y = x1r * r1v.y - x1i * r1v.x;
    }
    ax += n0 * p0x + n1 * p1x; ay += n0 * p0y + n1 * p1y;
  }
  if (i < end) {
    uint2 r0 = csr[i];
    int s0 = r0.x & 0x1FFFF, t0 = r0.x >> 17;
    H16 c0; c0.u = (unsigned short)(r0.y >> 16);
    float n0 = (float)c0.h;
    f16x2 x0 = ((const f16x2*)(Abuf + (size_t)s0 * 384 + 256))[l];
    float2 r0v = R2[t0 * 64 + l];
    float x0r = (float)x0[0], x0i = (float)x0[1];
    float px, py;
    if (l == 0) { px = x0r * r0v.x; py = x0i * r0v.y; }
    else { px = x0r * r0v.x + x0i * r0v.y; py = x0r * r0v.y - x0i * r0v.x; }
    ax += n0 * px; ay += n0 * py;
  }
}

__global__ __launch_bounds__(256) void k_agg(
    _Float16* __restrict__ Abuf, const float* __restrict__ Rf,
    const uint2* __restrict__ csrIn, const int* __restrict__ offIn,
    const uint2* __restrict__ csrOut, const int* __restrict__ offOut) {
  int w = threadIdx.x >> 6, l = threadIdx.x & 63;
  int v = blockIdx.x * 4 + w;
  if (v >= N_ENT) return;
  const float2* R2 = (const float2*)Rf;
  float cix = 0.f, ciy = 0.f, cox = 0.f, coy = 0.f;
  aggdir(csrIn, offIn[v], offIn[v + 1], l, Abuf, R2, cix, ciy);
  aggdir(csrOut, offOut[v], offOut[v + 1], l, Abuf, R2, cox, coy);
  ((f16x2*)(Abuf + (size_t)v * 384))[l]       = (f16x2){(_Float16)cix, (_Float16)ciy};
  ((f16x2*)(Abuf + (size_t)v * 384 + 128))[l] = (f16x2){(_Float16)cox, (_Float16)coy};
}

// ---------------- batch norm ----------------
__global__ void k_bnfin(const float* __restrict__ bnAcc, const float* __restrict__ bnw,
                        const float* __restrict__ bnb, float* __restrict__ ss) {
  int c = threadIdx.x;
  float mu = bnAcc[c] * (1.f / (float)N_ENT);
  float var = bnAcc[128 + c] * (1.f / (float)N_ENT) - mu * mu;
  float sc = bnw[c] * rsqrtf(var + 1e-5f);
  ss[c] = sc; ss[128 + c] = bnb[c] - mu * sc;
}

__global__ void k_norm(float* __restrict__ out, const float* __restrict__ ss) {
  int i = blockIdx.x * 256 + threadIdx.x;
  float4* o = (float4*)out;
  float4 v = o[i];
  int c = (i & 31) * 4;
  v.x = v.x * ss[c]     + ss[128 + c];
  v.y = v.y * ss[c + 1] + ss[129 + c];
  v.z = v.z * ss[c + 2] + ss[130 + c];
  v.w = v.w * ss[c + 3] + ss[131 + c];
  o[i] = v;
}

extern "C" void kernel_launch(void* const* d_in, const int* in_sizes, int n_in,
                              void* d_out, int out_size, void* d_ws, size_t ws_size,
                              hipStream_t stream) {
  const float* x       = (const float*)d_in[0];
  const float* rel     = (const float*)d_in[1];
  const float* w_in    = (const float*)d_in[2];
  const float* w_out   = (const float*)d_in[3];
  const float* w_loop  = (const float*)d_in[4];
  const float* w_rel   = (const float*)d_in[5];
  const float* looprel = (const float*)d_in[6];
  const float* bias    = (const float*)d_in[7];
  const float* bnw     = (const float*)d_in[8];
  const float* bnb     = (const float*)d_in[9];
  const int*   ei      = (const int*)d_in[10];
  const int*   et      = (const int*)d_in[11];
  float* out = (float*)d_out;

  char* p = (char*)d_ws;
  auto alloc = [&](size_t bytes) -> void* {
    void* r = (void*)p;
    p += (bytes + 255) & ~(size_t)255;
    return r;
  };
  const size_t RECCAP = EHALF + NBUK * 776;  // padded coarse regions
  _Float16* Abuf  = (_Float16*)alloc((size_t)N_ENT * 384 * 2);
  _Float16* WT    = (_Float16*)alloc(128 * 384 * 2);
  _Float16* FtabT = (_Float16*)alloc(128 * 128 * 2);
  float* Wstack   = (float*)alloc(384 * 128 * 4);
  float* Ftab     = (float*)alloc(128 * 128 * 4);
  float* Gtab     = (float*)alloc(128 * 128 * 4);
  float* Rf       = (float*)alloc(501 * 128 * 4);
  int*   degIn    = (int*)alloc(N_ENT * 4);
  int*   degOut   = (int*)alloc(N_ENT * 4);
  float* dinvIn   = (float*)alloc(N_ENT * 4);
  float* dinvOut  = (float*)alloc(N_ENT * 4);
  int*   bcntIn   = (int*)alloc(NBUK * 4);
  int*   bcntOut  = (int*)alloc(NBUK * 4);
  int*   boffIn   = (int*)alloc(NBUK * 4);
  int*   boffOut  = (int*)alloc(NBUK * 4);
  int*   gcurIn   = (int*)alloc(NBUK * 4);
  int*   gcurOut  = (int*)alloc(NBUK * 4);
  int*   csrBIn   = (int*)alloc((NBUK + 1) * 4);
  int*   csrBOut  = (int*)alloc((NBUK + 1) * 4);
  int*   offFineIn  = (int*)alloc((N_ENT + 1) * 4);
  int*   offFineOut = (int*)alloc((N_ENT + 1) * 4);
  uint2* recInC   = (uint2*)alloc(RECCAP * 8);
  uint2* recOutC  = (uint2*)alloc(RECCAP * 8);
  uint2* csrIn    = (uint2*)alloc((size_t)EHALF * 8);
  uint2* csrOut   = (uint2*)alloc((size_t)EHALF * 8);
  float* bnAcc    = (float*)alloc(256 * 4);
  float* ss       = (float*)alloc(256 * 4);

  hipMemsetAsync(degIn, 0, N_ENT * 4, stream);
  hipMemsetAsync(degOut, 0, N_ENT * 4, stream);
  hipMemsetAsync(bcntIn, 0, NBUK * 4, stream);
  hipMemsetAsync(bcntOut, 0, NBUK * 4, stream);
  hipMemsetAsync(bnAcc, 0, 256 * 4, stream);

  // tables + relation spectra + folded weight stack
  k_tabs<<<64, 256, 0, stream>>>(Ftab, Gtab, FtabT);
  k_dftrel<<<501, 128, 0, stream>>>(rel, looprel, Ftab, Rf);
  gemm128<<<2, 256, 0, stream>>>(Gtab, 128, w_in,   Wstack,             128, 128, 128);
  gemm128<<<2, 256, 0, stream>>>(Gtab, 128, w_out,  Wstack + 128 * 128, 128, 128, 128);
  gemm128<<<2, 256, 0, stream>>>(Gtab, 128, w_loop, Wstack + 256 * 128, 128, 128, 128);
  k_rotloop<<<64, 128, 0, stream>>>(Wstack + 256 * 128, Rf + 500 * 128);
  k_wt<<<192, 256, 0, stream>>>(Wstack, WT, 384);

  // Xf = rfft(x) via f16 MFMA (A read as fp32, converted in-kernel)
  mgemm<128, 128, true, false, float><<<(N_ENT + 255) / 256, 256, 0, stream>>>(
      x, 128, FtabT, (void*)(Abuf + 256), 384, N_ENT, nullptr, nullptr);

  // degrees + coarse bucket counts
  k_hist<<<512, 256, 0, stream>>>(ei, degIn, degOut, bcntIn, bcntOut);
  k_dinv2<<<(2 * N_ENT + 255) / 256, 256, 0, stream>>>(degIn, degOut, dinvIn, dinvOut);
  k_bscan<<<1, 256, 0, stream>>>(bcntIn, bcntOut, boffIn, gcurIn, csrBIn,
                                 boffOut, gcurOut, csrBOut, offFineIn, offFineOut);

  // coarse split (write-amp-free), then fine CSR sort per bucket
  k_split<<<256, 256, 0, stream>>>(ei,         ei + 2 * EHALF, et,         dinvIn,  gcurIn,  recInC);
  k_split<<<256, 256, 0, stream>>>(ei + EHALF, ei + 3 * EHALF, et + EHALF, dinvOut, gcurOut, recOutC);
  k_fsort<<<2 * NBUK, 512, 0, stream>>>(recInC, boffIn, gcurIn, csrBIn, csrIn, offFineIn,
                                        recOutC, boffOut, gcurOut, csrBOut, csrOut, offFineOut);

  // frequency-domain aggregation
  k_agg<<<N_ENT / 4, 256, 0, stream>>>(Abuf, Rf, csrIn, offFineIn, csrOut, offFineOut);

  // fused output GEMM (f16 MFMA): [c_in|c_out|Xf] @ Wstack + bias, BN stats
  mgemm<384, 192, false, true, _Float16><<<(N_ENT + 255) / 256, 256, 0, stream>>>(
      Abuf, 384, WT, (void*)out, 128, N_ENT, bias, bnAcc);
  k_bnfin<<<1, 128, 0, stream>>>(bnAcc, bnw, bnb, ss);
  k_norm<<<(N_ENT * 128 / 4) / 256, 256, 0, stream>>>(out, ss);

  // rel_out = rel_embed @ w_rel (fp32)
  gemm128<<<(N_REL + 63) / 64, 256, 0, stream>>>(rel, 128, w_rel, out + (size_t)N_ENT * 128, 128, N_REL, 128);
}